// Round 13
// baseline (486.090 us; speedup 1.0000x reference)
//
#include <hip/hip_runtime.h>
#include <math.h>

#define TPB 256
#define NBX 256    // k_stats_x grid
#define NBE 1024   // k_edge0 grid
#define CONVB 2048 // persistent conv blocks

typedef unsigned short u16;

__device__ __forceinline__ float lrelu(float v){ return fmaxf(v, 0.2f*v); }
#define RF(x) __builtin_amdgcn_readfirstlane(x)

// pack two floats to bf16 (RNE) in one uint
__device__ __forceinline__ unsigned pack_bf16(float a, float b){
  unsigned ua = __float_as_uint(a), ub = __float_as_uint(b);
  ua = (ua + 0x7FFFu + ((ua >> 16) & 1u)) >> 16;
  ub = (ub + 0x7FFFu + ((ub >> 16) & 1u)) >> 16;
  return ua | (ub << 16);
}

// ---------------- BN statistics (two-stage deterministic reduce) ----------------
// st layout (floats): [40..55] scale_n [56..71] shift_n [72..75] scale_e [76..79] shift_e
__global__ __launch_bounds__(TPB) void k_stats_x(const float* __restrict__ x, float* __restrict__ px, int n){
  __shared__ float lds[4*32];
  int tid = blockIdx.x*blockDim.x + threadIdx.x;
  int stride = gridDim.x*blockDim.x;
  float s[16], q[16];
  #pragma unroll
  for (int i=0;i<16;++i){ s[i]=0.f; q[i]=0.f; }
  for (int r=tid; r<n; r+=stride){
    const float4* p = (const float4*)(x + (long)r*16);
    #pragma unroll
    for (int j=0;j<4;++j){
      float4 v = p[j];
      s[j*4+0]+=v.x; q[j*4+0]+=v.x*v.x;
      s[j*4+1]+=v.y; q[j*4+1]+=v.y*v.y;
      s[j*4+2]+=v.z; q[j*4+2]+=v.z*v.z;
      s[j*4+3]+=v.w; q[j*4+3]+=v.w*v.w;
    }
  }
  int wid = threadIdx.x >> 6, lane = threadIdx.x & 63;
  #pragma unroll
  for (int i=0;i<32;++i){
    float v = (i<16) ? s[i] : q[i-16];
    #pragma unroll
    for (int m=1;m<64;m<<=1) v += __shfl_xor(v, m);
    if (lane==0) lds[wid*32+i] = v;
  }
  __syncthreads();
  if (threadIdx.x < 32){
    float v = lds[threadIdx.x] + lds[32+threadIdx.x] + lds[64+threadIdx.x] + lds[96+threadIdx.x];
    px[blockIdx.x*32 + threadIdx.x] = v;
  }
}

// fused: edge-attr BN stats + dst histogram + per-edge rank (atomicAdd return)
__global__ __launch_bounds__(TPB) void k_edge0(const float* __restrict__ ea, const int* __restrict__ ei,
                      float* __restrict__ pe, int* __restrict__ cnt, int* __restrict__ rank, int E){
  __shared__ float lds[4*8];
  int tid = blockIdx.x*blockDim.x + threadIdx.x;
  int stride = gridDim.x*blockDim.x;
  float s[4]={0,0,0,0}, q[4]={0,0,0,0};
  for (int r=tid; r<E; r+=stride){
    float4 v = ((const float4*)ea)[r];
    s[0]+=v.x; q[0]+=v.x*v.x;
    s[1]+=v.y; q[1]+=v.y*v.y;
    s[2]+=v.z; q[2]+=v.z*v.z;
    s[3]+=v.w; q[3]+=v.w*v.w;
    int d = ei[E + r];
    rank[r] = atomicAdd(&cnt[d], 1);
  }
  int wid = threadIdx.x >> 6, lane = threadIdx.x & 63;
  #pragma unroll
  for (int i=0;i<8;++i){
    float v = (i<4) ? s[i] : q[i-4];
    #pragma unroll
    for (int m=1;m<64;m<<=1) v += __shfl_xor(v, m);
    if (lane==0) lds[wid*8+i] = v;
  }
  __syncthreads();
  if (threadIdx.x < 8){
    float v = lds[threadIdx.x] + lds[8+threadIdx.x] + lds[16+threadIdx.x] + lds[24+threadIdx.x];
    pe[blockIdx.x*8 + threadIdx.x] = v;
  }
}

__global__ __launch_bounds__(TPB) void k_finalize(const float* __restrict__ g_n, const float* __restrict__ b_n,
                           const float* __restrict__ g_e, const float* __restrict__ b_e,
                           const float* __restrict__ px, const float* __restrict__ pe,
                           float* __restrict__ st, int n, int e){
  __shared__ float lx[256], le[256];
  int t = threadIdx.x;
  {  // x: counter c = t&31, chunk = t>>5 (8 chunks x 32 blocks = NBX)
    int c = t & 31, ch = t >> 5;
    float sx = 0.f;
    for (int b = ch*32; b < ch*32+32; ++b) sx += px[b*32 + c];
    lx[t] = sx;
  }
  {  // e: counter c = t&7, chunk = t>>3 (32 chunks x 32 blocks = NBE)
    int c = t & 7, ch = t >> 3;
    float se = 0.f;
    for (int b = ch*32; b < ch*32+32; ++b) se += pe[b*8 + c];
    le[t] = se;
  }
  __syncthreads();
  if (t < 16){
    float sum = 0.f, sq = 0.f;
    #pragma unroll
    for (int ch=0; ch<8; ++ch){ sum += lx[ch*32 + t]; sq += lx[ch*32 + 16 + t]; }
    float mean = sum / (float)n;
    float var  = sq / (float)n - mean*mean;
    float sc = g_n[t] * rsqrtf(var + 1e-5f);
    st[40+t] = sc; st[56+t] = b_n[t] - mean*sc;
  } else if (t < 20){
    int f = t-16;
    float sum = 0.f, sq = 0.f;
    #pragma unroll
    for (int ch=0; ch<32; ++ch){ sum += le[ch*8 + f]; sq += le[ch*8 + 4 + f]; }
    float mean = sum / (float)e;
    float var  = sq / (float)e - mean*mean;
    float sc = g_e[f] * rsqrtf(var + 1e-5f);
    st[72+f] = sc; st[76+f] = b_e[f] - mean*sc;
  }
}

// rp[i] = prefix(cnt)[i] + i  -> each node's segment has deg+1 slots (self loop last)
__global__ __launch_bounds__(TPB) void k_scan_a(const int* __restrict__ cnt, int* __restrict__ rp,
                                                int* __restrict__ part, int n){
  __shared__ int lds[TPB];
  int t = threadIdx.x;
  int base = blockIdx.x*2048 + t*8;
  int v[8]; int run = 0;
  #pragma unroll
  for (int j=0;j<8;++j){
    int idx = base + j;
    v[j] = run;
    run += (idx < n) ? cnt[idx] : 0;
  }
  lds[t] = run;
  __syncthreads();
  for (int off=1; off<TPB; off<<=1){
    int add = (t >= off) ? lds[t-off] : 0;
    __syncthreads();
    lds[t] += add;
    __syncthreads();
  }
  int excl = lds[t] - run;
  if (t == TPB-1) part[blockIdx.x] = lds[t];
  #pragma unroll
  for (int j=0;j<8;++j){
    int idx = base + j;
    if (idx < n) rp[idx] = v[j] + excl + idx;   // +idx: self-loop slots
  }
}

// finalize rp: each thread sums its chunk's part-prefix from the (L1-hot) part
// array — replaces the serial 1-thread scan_b kernel + a launch.
__global__ __launch_bounds__(TPB) void k_scan_c(int* __restrict__ rp, const int* __restrict__ part, int n, int nb){
  int idx = blockIdx.x*blockDim.x + threadIdx.x;
  if (idx < n){
    int chunk = idx >> 11;
    int add = 0;
    for (int b = 0; b < chunk; ++b) add += part[b];
    rp[idx] += add;
  } else if (idx == n){
    int tot = 0;
    for (int b = 0; b < nb; ++b) tot += part[b];
    rp[n] = tot + n;
  }
}

// atomic-free scatter: pos = rp[dst] + rank (rank recorded during k_edge0).
// Plain store: csr_se is read right after by k_post — keep it L2-resident.
__global__ __launch_bounds__(TPB) void k_scatter(const int* __restrict__ ei, const int* __restrict__ rank,
                        const int* __restrict__ rp, int2* __restrict__ csr_se, int E){
  for (int e = blockIdx.x*blockDim.x + threadIdx.x; e < E; e += gridDim.x*blockDim.x){
    int srcv = ei[e];
    int d    = ei[E + e];
    int pos = rp[d] + rank[e];
    csr_se[pos] = make_int2(srcv, e);
  }
}

// per-node expansion: 16 lanes per node (deg~10). csr_se -> csr_src + normalized
// csr_ea, plus self-loop entry {src=node, ea=mean of incoming} at segment end.
__global__ __launch_bounds__(TPB) void k_post(const int2* __restrict__ csr_se, const float4* __restrict__ ea,
                        const float* __restrict__ st, const int* __restrict__ rp,
                        int* __restrict__ csr_src, float4* __restrict__ csr_ea, int n){
  int lane = threadIdx.x & 63;
  int l16 = lane & 15;
  int node = (blockIdx.x*4 + (threadIdx.x >> 6))*4 + (lane >> 4);
  if (node >= n) return;
  float s0=st[72], s1=st[73], s2=st[74], s3=st[75];
  float h0=st[76], h1=st[77], h2=st[78], h3=st[79];
  int ib = rp[node], ie1 = rp[node+1] - 1;   // real edges [ib, ie1), self slot at ie1
  float4 sum = make_float4(0.f,0.f,0.f,0.f);
  for (int i = ib + l16; i < ie1; i += 16){
    int2 se = csr_se[i];
    float4 v = ea[se.y];
    float4 nv = make_float4(fmaf(v.x,s0,h0), fmaf(v.y,s1,h1), fmaf(v.z,s2,h2), fmaf(v.w,s3,h3));
    csr_src[i] = se.x;
    csr_ea[i] = nv;
    sum.x += nv.x; sum.y += nv.y; sum.z += nv.z; sum.w += nv.w;
  }
  #pragma unroll
  for (int m=1;m<16;m<<=1){
    sum.x += __shfl_xor(sum.x, m);
    sum.y += __shfl_xor(sum.y, m);
    sum.z += __shfl_xor(sum.z, m);
    sum.w += __shfl_xor(sum.w, m);
  }
  if (l16 == 0){
    int deg = ie1 - ib;
    float ic = 1.f / fmaxf((float)deg, 1.f);
    csr_src[ie1] = node;
    csr_ea[ie1] = make_float4(sum.x*ic, sum.y*ic, sum.z*ic, sum.w*ic);
  }
}

// ---------------- dual GEMM: xl(bf16) = X@Wl+bl, xr(f32) = X@Wr+br -------------
// float4 X-loads into NAMED variables (no arrays/pointer-selects — R8 lesson).
// xl written as packed bf16 rows (128B/row) to halve the conv gather bytes.
#define FMA16(i, xv) {                          \
    acc[i][0]  = fmaf(xv, wa.x, acc[i][0]);     \
    acc[i][1]  = fmaf(xv, wa.y, acc[i][1]);     \
    acc[i][2]  = fmaf(xv, wa.z, acc[i][2]);     \
    acc[i][3]  = fmaf(xv, wa.w, acc[i][3]);     \
    acc[i][4]  = fmaf(xv, wb.x, acc[i][4]);     \
    acc[i][5]  = fmaf(xv, wb.y, acc[i][5]);     \
    acc[i][6]  = fmaf(xv, wb.z, acc[i][6]);     \
    acc[i][7]  = fmaf(xv, wb.w, acc[i][7]);     \
    acc[i][8]  = fmaf(xv, wc.x, acc[i][8]);     \
    acc[i][9]  = fmaf(xv, wc.y, acc[i][9]);     \
    acc[i][10] = fmaf(xv, wc.z, acc[i][10]);    \
    acc[i][11] = fmaf(xv, wc.w, acc[i][11]);    \
    acc[i][12] = fmaf(xv, wd.x, acc[i][12]);    \
    acc[i][13] = fmaf(xv, wd.y, acc[i][13]);    \
    acc[i][14] = fmaf(xv, wd.z, acc[i][14]);    \
    acc[i][15] = fmaf(xv, wd.w, acc[i][15]); }
#define KSTEP(kk, c0_, c1_, c2_, c3_) {                                        \
    const float4* w4 = (const float4*)&Wlds[(k4*4+kk)*128 + c16];              \
    float4 wa = w4[0], wb = w4[1], wc = w4[2], wd = w4[3];                     \
    FMA16(0, c0_); FMA16(1, c1_); FMA16(2, c2_); FMA16(3, c3_); }

template<int K, bool BN>
__global__ __launch_bounds__(TPB) void k_gemm(const float* __restrict__ X,
    const float* __restrict__ Wl, const float* __restrict__ bl,
    const float* __restrict__ Wr, const float* __restrict__ br,
    const float* __restrict__ st,
    u16* __restrict__ xl, float* __restrict__ xr, int nrows){
  __shared__ __align__(16) float Wlds[K*128];
  __shared__ float blds[128];
  __shared__ float bns[16], bnb[16];
  int t = threadIdx.x;
  for (int idx = t; idx < K*128; idx += TPB){
    int k = idx >> 7, j = idx & 127;
    Wlds[idx] = (j < 64) ? Wl[k*64 + j] : Wr[k*64 + (j - 64)];
  }
  if (t < 64) blds[t] = bl[t];
  else if (t < 128) blds[t] = br[t - 64];
  if (BN){ if (t >= 128 && t < 144){ bns[t-128] = st[40 + (t-128)]; bnb[t-128] = st[56 + (t-128)]; } }
  __syncthreads();
  int rg = t & 31, c = t >> 5;
  int c16 = c*16;
  int r0 = blockIdx.x*128 + rg*4;
  int r[4];
  #pragma unroll
  for (int i=0;i<4;++i){ int ri = r0 + i; r[i] = (ri < nrows) ? ri : (nrows-1); }
  float acc[4][16];
  #pragma unroll
  for (int i=0;i<4;++i){
    #pragma unroll
    for (int j=0;j<16;++j) acc[i][j]=0.f;
  }
  #pragma unroll 2
  for (int k4=0; k4<K/4; ++k4){
    float4 xa = *(const float4*)&X[(size_t)r[0]*K + k4*4];
    float4 xb = *(const float4*)&X[(size_t)r[1]*K + k4*4];
    float4 xc = *(const float4*)&X[(size_t)r[2]*K + k4*4];
    float4 xd = *(const float4*)&X[(size_t)r[3]*K + k4*4];
    if (BN){
      float s0=bns[k4*4+0], b0=bnb[k4*4+0];
      float s1=bns[k4*4+1], b1=bnb[k4*4+1];
      float s2=bns[k4*4+2], b2=bnb[k4*4+2];
      float s3=bns[k4*4+3], b3=bnb[k4*4+3];
      xa.x=fmaf(xa.x,s0,b0); xa.y=fmaf(xa.y,s1,b1); xa.z=fmaf(xa.z,s2,b2); xa.w=fmaf(xa.w,s3,b3);
      xb.x=fmaf(xb.x,s0,b0); xb.y=fmaf(xb.y,s1,b1); xb.z=fmaf(xb.z,s2,b2); xb.w=fmaf(xb.w,s3,b3);
      xc.x=fmaf(xc.x,s0,b0); xc.y=fmaf(xc.y,s1,b1); xc.z=fmaf(xc.z,s2,b2); xc.w=fmaf(xc.w,s3,b3);
      xd.x=fmaf(xd.x,s0,b0); xd.y=fmaf(xd.y,s1,b1); xd.z=fmaf(xd.z,s2,b2); xd.w=fmaf(xd.w,s3,b3);
    }
    KSTEP(0, xa.x, xb.x, xc.x, xd.x);
    KSTEP(1, xa.y, xb.y, xc.y, xd.y);
    KSTEP(2, xa.z, xb.z, xc.z, xd.z);
    KSTEP(3, xa.w, xb.w, xc.w, xd.w);
  }
  if (c16 < 64){
    // xl: pack 16 biased outputs to bf16, two uint4 stores per row
    #pragma unroll
    for (int i=0;i<4;++i){
      if (r0 + i < nrows){
        u16* qb = &xl[(size_t)(r0+i)*64 + c16];
        uint4 p0, p1;
        p0.x = pack_bf16(acc[i][0] +blds[c16+0],  acc[i][1] +blds[c16+1]);
        p0.y = pack_bf16(acc[i][2] +blds[c16+2],  acc[i][3] +blds[c16+3]);
        p0.z = pack_bf16(acc[i][4] +blds[c16+4],  acc[i][5] +blds[c16+5]);
        p0.w = pack_bf16(acc[i][6] +blds[c16+6],  acc[i][7] +blds[c16+7]);
        p1.x = pack_bf16(acc[i][8] +blds[c16+8],  acc[i][9] +blds[c16+9]);
        p1.y = pack_bf16(acc[i][10]+blds[c16+10], acc[i][11]+blds[c16+11]);
        p1.z = pack_bf16(acc[i][12]+blds[c16+12], acc[i][13]+blds[c16+13]);
        p1.w = pack_bf16(acc[i][14]+blds[c16+14], acc[i][15]+blds[c16+15]);
        ((uint4*)qb)[0] = p0;
        ((uint4*)qb)[1] = p1;
      }
    }
  } else {
    int cb = c16 - 64;
    #pragma unroll
    for (int i=0;i<4;++i){
      if (r0 + i < nrows){
        float* q = &xr[(size_t)(r0+i)*64 + cb];
        ((float4*)q)[0] = make_float4(acc[i][0]+blds[c16+0],  acc[i][1]+blds[c16+1],
                                      acc[i][2]+blds[c16+2],  acc[i][3]+blds[c16+3]);
        ((float4*)q)[1] = make_float4(acc[i][4]+blds[c16+4],  acc[i][5]+blds[c16+5],
                                      acc[i][6]+blds[c16+6],  acc[i][7]+blds[c16+7]);
        ((float4*)q)[2] = make_float4(acc[i][8]+blds[c16+8],  acc[i][9]+blds[c16+9],
                                      acc[i][10]+blds[c16+10],acc[i][11]+blds[c16+11]);
        ((float4*)q)[3] = make_float4(acc[i][12]+blds[c16+12],acc[i][13]+blds[c16+13],
                                      acc[i][14]+blds[c16+14],acc[i][15]+blds[c16+15]);
      }
    }
  }
}

// ---------------- GATv2 conv: 4 channels/lane, 4 edges/wave -------------------
// Quarter q = lane>>4 owns edge (i+q); each lane holds channels 4*l16..4*l16+3
// as one uint2 (bf16x4) gather — dword-class, 16 lanes x 8B = 128B/row.
// Head h = channels 8h..8h+7 = lanes {2h,2h+1}: reduce = shfl_xor(p,1).
// One exp per lane per 4 edges. Quarters combined per node via shfl_xor 16/32.
#define LOADQ(e_, u_, i_) { int idx_ = (i_) + qq; int s_ = csr_src[idx_];       \
    e_ = csr_ea[idx_];                                                          \
    u_ = *(const uint2*)&xl[(size_t)s_*64 + (l16<<2)]; }
#define PROCQ(e_, u_) {                                                         \
    float a0_ = __uint_as_float((u_).x << 16);                                  \
    float a1_ = __uint_as_float((u_).x & 0xffff0000u);                          \
    float a2_ = __uint_as_float((u_).y << 16);                                  \
    float a3_ = __uint_as_float((u_).y & 0xffff0000u);                          \
    float v0_ = a0_ + xr4.x, v1_ = a1_ + xr4.y;                                 \
    float v2_ = a2_ + xr4.z, v3_ = a3_ + xr4.w;                                 \
    v0_ = fmaf(e_.x,we0.x, fmaf(e_.y,we1.x, fmaf(e_.z,we2.x, fmaf(e_.w,we3.x, v0_)))); \
    v1_ = fmaf(e_.x,we0.y, fmaf(e_.y,we1.y, fmaf(e_.z,we2.y, fmaf(e_.w,we3.y, v1_)))); \
    v2_ = fmaf(e_.x,we0.z, fmaf(e_.y,we1.z, fmaf(e_.z,we2.z, fmaf(e_.w,we3.z, v2_)))); \
    v3_ = fmaf(e_.x,we0.w, fmaf(e_.y,we1.w, fmaf(e_.z,we2.w, fmaf(e_.w,we3.w, v3_)))); \
    v0_=lrelu(v0_); v1_=lrelu(v1_); v2_=lrelu(v2_); v3_=lrelu(v3_);             \
    float p_ = fmaf(v0_,att4.x, fmaf(v1_,att4.y, fmaf(v2_,att4.z, v3_*att4.w))); \
    p_ += __shfl_xor(p_, 1);                                                    \
    float w_ = __expf(p_);                                                      \
    S += w_;                                                                    \
    O0 = fmaf(w_,a0_,O0); O1 = fmaf(w_,a1_,O1);                                 \
    O2 = fmaf(w_,a2_,O2); O3 = fmaf(w_,a3_,O3); }

__global__ __launch_bounds__(TPB) void k_conv(
    const u16* __restrict__ xl, const float* __restrict__ xr,
    const int* __restrict__ rp, const int* __restrict__ csr_src, const float4* __restrict__ csr_ea,
    const float* __restrict__ We, const float* __restrict__ att, const float* __restrict__ bc,
    float* __restrict__ xout, int n){
  int lane = threadIdx.x & 63;
  int qq  = lane >> 4;          // edge quarter 0..3
  int l16 = lane & 15;
  int c0 = l16*4;
  int gw = blockIdx.x*4 + (threadIdx.x >> 6);
  int nw = gridDim.x*4;
  float4 we0 = *(const float4*)&We[c0];
  float4 we1 = *(const float4*)&We[64+c0];
  float4 we2 = *(const float4*)&We[128+c0];
  float4 we3 = *(const float4*)&We[192+c0];
  float4 att4 = *(const float4*)&att[c0];
  float4 bc4  = *(const float4*)&bc[c0];

  for (int node = gw; node < n; node += nw){
    int ib = RF(rp[node]);
    int ie = RF(rp[node+1]);
    int cnt = ie - ib;
    float4 xr4 = *(const float4*)&xr[(size_t)node*64 + c0];
    float S = 0.f, O0 = 0.f, O1 = 0.f, O2 = 0.f, O3 = 0.f;
    float4 e0, e1; uint2 u0 = {0,0}, u1 = {0,0};
    int nq = cnt >> 2;                 // full quads
    int iendf = ib + (nq << 2);
    int rem = cnt & 3;
    if (nq > 0) LOADQ(e0,u0, ib);
    if (nq > 1) LOADQ(e1,u1, ib+4);
    int i = ib;
    for (; i+8 <= iendf; i += 8){
      PROCQ(e0,u0); if (i+8  < iendf) LOADQ(e0,u0, i+8);
      PROCQ(e1,u1); if (i+12 < iendf) LOADQ(e1,u1, i+12);
    }
    if (iendf - i >= 4) PROCQ(e0,u0);  // 0 or 1 remaining full quad
    if (rem){
      // tail: quarters q >= rem read a clamped duplicate; their w is masked to 0
      int idx_ = min(iendf + qq, ie - 1);
      int s_ = csr_src[idx_];
      float4 et = csr_ea[idx_];
      uint2 ut = *(const uint2*)&xl[(size_t)s_*64 + (l16<<2)];
      float a0_ = __uint_as_float(ut.x << 16);
      float a1_ = __uint_as_float(ut.x & 0xffff0000u);
      float a2_ = __uint_as_float(ut.y << 16);
      float a3_ = __uint_as_float(ut.y & 0xffff0000u);
      float v0_ = a0_ + xr4.x, v1_ = a1_ + xr4.y;
      float v2_ = a2_ + xr4.z, v3_ = a3_ + xr4.w;
      v0_ = fmaf(et.x,we0.x, fmaf(et.y,we1.x, fmaf(et.z,we2.x, fmaf(et.w,we3.x, v0_))));
      v1_ = fmaf(et.x,we0.y, fmaf(et.y,we1.y, fmaf(et.z,we2.y, fmaf(et.w,we3.y, v1_))));
      v2_ = fmaf(et.x,we0.z, fmaf(et.y,we1.z, fmaf(et.z,we2.z, fmaf(et.w,we3.z, v2_))));
      v3_ = fmaf(et.x,we0.w, fmaf(et.y,we1.w, fmaf(et.z,we2.w, fmaf(et.w,we3.w, v3_))));
      v0_=lrelu(v0_); v1_=lrelu(v1_); v2_=lrelu(v2_); v3_=lrelu(v3_);
      float p_ = fmaf(v0_,att4.x, fmaf(v1_,att4.y, fmaf(v2_,att4.z, v3_*att4.w)));
      p_ += __shfl_xor(p_, 1);
      float w_ = (qq < rem) ? __expf(p_) : 0.f;
      S += w_;
      O0 = fmaf(w_,a0_,O0); O1 = fmaf(w_,a1_,O1);
      O2 = fmaf(w_,a2_,O2); O3 = fmaf(w_,a3_,O3);
    }
    // combine the four edge-quarters
    S  += __shfl_xor(S, 16);  S  += __shfl_xor(S, 32);
    O0 += __shfl_xor(O0,16);  O0 += __shfl_xor(O0,32);
    O1 += __shfl_xor(O1,16);  O1 += __shfl_xor(O1,32);
    O2 += __shfl_xor(O2,16);  O2 += __shfl_xor(O2,32);
    O3 += __shfl_xor(O3,16);  O3 += __shfl_xor(O3,32);
    if (qq == 0){
      float inv = 1.f / S;
      float4 o;
      o.x = lrelu(fmaf(O0, inv, bc4.x));
      o.y = lrelu(fmaf(O1, inv, bc4.y));
      o.z = lrelu(fmaf(O2, inv, bc4.z));
      o.w = lrelu(fmaf(O3, inv, bc4.w));
      *(float4*)&xout[(size_t)node*64 + c0] = o;
    }
  }
}

// ---------------- fused readout: one block per graph ----------------
// batch is sorted -> group g occupies a contiguous range found by binary search.
__global__ __launch_bounds__(1024) void k_readout(const float* __restrict__ x,
    const int* __restrict__ batch, const float* __restrict__ tin,
    const float* __restrict__ Wout, const float* __restrict__ bout,
    float* __restrict__ out, int n){
  int g = blockIdx.x;
  int lane = threadIdx.x & 63, wid = threadIdx.x >> 6;   // 16 waves
  int lo, hi;
  { int a=0, b=n; while (a<b){ int m=(a+b)>>1; if (batch[m] <  g) a=m+1; else b=m; } lo=a; }
  { int a=lo, b=n; while (a<b){ int m=(a+b)>>1; if (batch[m] <= g) a=m+1; else b=m; } hi=a; }
  float t = tin[0];
  __shared__ float red[16][64];
  float mx = -INFINITY;
  for (int nd = lo + wid; nd < hi; nd += 16)
    mx = fmaxf(mx, x[(size_t)nd*64 + lane]*t);
  red[wid][lane] = mx;
  __syncthreads();
  mx = -INFINITY;
  #pragma unroll
  for (int wv=0; wv<16; ++wv) mx = fmaxf(mx, red[wv][lane]);
  __syncthreads();
  float ld = 0.f, ln = 0.f;
  for (int nd = lo + wid; nd < hi; nd += 16){
    float xv = x[(size_t)nd*64 + lane];
    float w = __expf(xv*t - mx);
    ld += w; ln = fmaf(w, xv, ln);
  }
  red[wid][lane] = ld;
  __syncthreads();
  float den = 0.f;
  #pragma unroll
  for (int wv=0; wv<16; ++wv) den += red[wv][lane];
  __syncthreads();
  red[wid][lane] = ln;
  __syncthreads();
  if (wid == 0){
    float num = 0.f;
    #pragma unroll
    for (int wv=0; wv<16; ++wv) num += red[wv][lane];
    float agg = (hi > lo) ? num/den : 0.f;
    #pragma unroll
    for (int c=0;c<4;++c){
      float p = agg * Wout[lane*4 + c];
      #pragma unroll
      for (int m=1;m<64;m<<=1) p += __shfl_xor(p, m);
      if (lane == 0) out[g*4 + c] = p + bout[c];
    }
  }
}

// ---------------- launch ----------------
extern "C" void kernel_launch(void* const* d_in, const int* in_sizes, int n_in,
                              void* d_out, int out_size, void* d_ws, size_t ws_size,
                              hipStream_t stream){
  const float* x     = (const float*)d_in[0];
  const int*   ei    = (const int*)d_in[1];
  const float* ea    = (const float*)d_in[2];
  const int*   batch = (const int*)d_in[3];
  const float* g_n = (const float*)d_in[4];
  const float* b_n = (const float*)d_in[5];
  const float* g_e = (const float*)d_in[6];
  const float* b_e = (const float*)d_in[7];
  const float* Wl[3]  = {(const float*)d_in[8],  (const float*)d_in[15], (const float*)d_in[22]};
  const float* bl[3]  = {(const float*)d_in[9],  (const float*)d_in[16], (const float*)d_in[23]};
  const float* Wr[3]  = {(const float*)d_in[10], (const float*)d_in[17], (const float*)d_in[24]};
  const float* br[3]  = {(const float*)d_in[11], (const float*)d_in[18], (const float*)d_in[25]};
  const float* We[3]  = {(const float*)d_in[12], (const float*)d_in[19], (const float*)d_in[26]};
  const float* att[3] = {(const float*)d_in[13], (const float*)d_in[20], (const float*)d_in[27]};
  const float* bc[3]  = {(const float*)d_in[14], (const float*)d_in[21], (const float*)d_in[28]};
  const float* tin  = (const float*)d_in[29];
  const float* Wout = (const float*)d_in[30];
  const float* bout = (const float*)d_in[31];
  float* out = (float*)d_out;

  const int n = in_sizes[0] / 16;   // nodes
  const int E = in_sizes[1] / 2;    // edges

  char* w = (char*)d_ws;
  size_t off = 0;
  auto alloc = [&](size_t bytes)->char*{
    char* p = w + off;
    off = (off + bytes + 255) & ~(size_t)255;
    return p;
  };
  int*      cnt      = (int*)alloc((size_t)n*4);       // must be zeroed
  size_t zero_end = off;
  float*    st       = (float*)alloc(128*4);
  int*      rank     = (int*)alloc((size_t)E*4);
  float*    px       = (float*)alloc((size_t)NBX*32*4);
  float*    pe       = (float*)alloc((size_t)NBE*8*4);
  int*      rp       = (int*)alloc(((size_t)n+1)*4);
  int*      part     = (int*)alloc(64*4);
  int2*     csr_se   = (int2*)alloc((size_t)(E+n)*8);
  int*      csr_src  = (int*)alloc((size_t)(E+n)*4);
  float4*   csr_ea   = (float4*)alloc((size_t)(E+n)*16);
  u16*      xlb      = (u16*)alloc((size_t)n*64*2);
  float*    xrb      = (float*)alloc((size_t)n*64*4);
  float*    xbuf     = (float*)alloc((size_t)n*64*4);
  if (off > ws_size) return;  // insufficient workspace -> clean (visible) failure

  hipMemsetAsync(d_ws, 0, zero_end, stream);

  k_stats_x<<<NBX, TPB, 0, stream>>>(x, px, n);
  k_edge0<<<NBE, TPB, 0, stream>>>(ea, ei, pe, cnt, rank, E);
  k_finalize<<<1, TPB, 0, stream>>>(g_n, b_n, g_e, b_e, px, pe, st, n, E);
  int nb = (n + 2047) / 2048;
  k_scan_a<<<nb, TPB, 0, stream>>>(cnt, rp, part, n);
  k_scan_c<<<(n + 1 + TPB - 1)/TPB, TPB, 0, stream>>>(rp, part, n, nb);
  k_scatter<<<2048, TPB, 0, stream>>>(ei, rank, rp, csr_se, E);
  k_post<<<(n + 15)/16, TPB, 0, stream>>>(csr_se, (const float4*)ea, st, rp, csr_src, (float4*)csr_ea, n);

  int gb = (n + 127)/128;
  for (int l=0; l<3; ++l){
    if (l == 0)
      k_gemm<16,true><<<gb, TPB, 0, stream>>>(x, Wl[0], bl[0], Wr[0], br[0], st, xlb, xrb, n);
    else
      k_gemm<64,false><<<gb, TPB, 0, stream>>>(xbuf, Wl[l], bl[l], Wr[l], br[l], st, xlb, xrb, n);
    k_conv<<<CONVB, TPB, 0, stream>>>(xlb, xrb, rp, csr_src, csr_ea,
                                      We[l], att[l], bc[l], xbuf, n);
  }

  k_readout<<<64, 1024, 0, stream>>>(xbuf, batch, tin, Wout, bout, out, n);
}

// Round 14
// 446.721 us; speedup vs baseline: 1.0881x; 1.0881x over previous
//
#include <hip/hip_runtime.h>
#include <math.h>

#define TPB 256
#define NBX 256    // k_stats_x grid
#define NBE 1024   // k_edge0 grid
#define CONVB 2048 // persistent conv blocks

typedef unsigned short u16;

__device__ __forceinline__ float lrelu(float v){ return fmaxf(v, 0.2f*v); }
#define RF(x) __builtin_amdgcn_readfirstlane(x)

// pack two floats to bf16 (RNE) in one uint
__device__ __forceinline__ unsigned pack_bf16(float a, float b){
  unsigned ua = __float_as_uint(a), ub = __float_as_uint(b);
  ua = (ua + 0x7FFFu + ((ua >> 16) & 1u)) >> 16;
  ub = (ub + 0x7FFFu + ((ub >> 16) & 1u)) >> 16;
  return ua | (ub << 16);
}

// ---------------- BN statistics (two-stage deterministic reduce) ----------------
// st layout (floats): [40..55] scale_n [56..71] shift_n [72..75] scale_e [76..79] shift_e
__global__ __launch_bounds__(TPB) void k_stats_x(const float* __restrict__ x, float* __restrict__ px, int n){
  __shared__ float lds[4*32];
  int tid = blockIdx.x*blockDim.x + threadIdx.x;
  int stride = gridDim.x*blockDim.x;
  float s[16], q[16];
  #pragma unroll
  for (int i=0;i<16;++i){ s[i]=0.f; q[i]=0.f; }
  for (int r=tid; r<n; r+=stride){
    const float4* p = (const float4*)(x + (long)r*16);
    #pragma unroll
    for (int j=0;j<4;++j){
      float4 v = p[j];
      s[j*4+0]+=v.x; q[j*4+0]+=v.x*v.x;
      s[j*4+1]+=v.y; q[j*4+1]+=v.y*v.y;
      s[j*4+2]+=v.z; q[j*4+2]+=v.z*v.z;
      s[j*4+3]+=v.w; q[j*4+3]+=v.w*v.w;
    }
  }
  int wid = threadIdx.x >> 6, lane = threadIdx.x & 63;
  #pragma unroll
  for (int i=0;i<32;++i){
    float v = (i<16) ? s[i] : q[i-16];
    #pragma unroll
    for (int m=1;m<64;m<<=1) v += __shfl_xor(v, m);
    if (lane==0) lds[wid*32+i] = v;
  }
  __syncthreads();
  if (threadIdx.x < 32){
    float v = lds[threadIdx.x] + lds[32+threadIdx.x] + lds[64+threadIdx.x] + lds[96+threadIdx.x];
    px[blockIdx.x*32 + threadIdx.x] = v;
  }
}

// fused: edge-attr BN stats + dst histogram + per-edge rank (atomicAdd return)
__global__ __launch_bounds__(TPB) void k_edge0(const float* __restrict__ ea, const int* __restrict__ ei,
                      float* __restrict__ pe, int* __restrict__ cnt, int* __restrict__ rank, int E){
  __shared__ float lds[4*8];
  int tid = blockIdx.x*blockDim.x + threadIdx.x;
  int stride = gridDim.x*blockDim.x;
  float s[4]={0,0,0,0}, q[4]={0,0,0,0};
  for (int r=tid; r<E; r+=stride){
    float4 v = ((const float4*)ea)[r];
    s[0]+=v.x; q[0]+=v.x*v.x;
    s[1]+=v.y; q[1]+=v.y*v.y;
    s[2]+=v.z; q[2]+=v.z*v.z;
    s[3]+=v.w; q[3]+=v.w*v.w;
    int d = ei[E + r];
    rank[r] = atomicAdd(&cnt[d], 1);
  }
  int wid = threadIdx.x >> 6, lane = threadIdx.x & 63;
  #pragma unroll
  for (int i=0;i<8;++i){
    float v = (i<4) ? s[i] : q[i-4];
    #pragma unroll
    for (int m=1;m<64;m<<=1) v += __shfl_xor(v, m);
    if (lane==0) lds[wid*8+i] = v;
  }
  __syncthreads();
  if (threadIdx.x < 8){
    float v = lds[threadIdx.x] + lds[8+threadIdx.x] + lds[16+threadIdx.x] + lds[24+threadIdx.x];
    pe[blockIdx.x*8 + threadIdx.x] = v;
  }
}

__global__ __launch_bounds__(TPB) void k_finalize(const float* __restrict__ g_n, const float* __restrict__ b_n,
                           const float* __restrict__ g_e, const float* __restrict__ b_e,
                           const float* __restrict__ px, const float* __restrict__ pe,
                           float* __restrict__ st, int n, int e){
  __shared__ float lx[256], le[256];
  int t = threadIdx.x;
  {  // x: counter c = t&31, chunk = t>>5 (8 chunks x 32 blocks = NBX)
    int c = t & 31, ch = t >> 5;
    float sx = 0.f;
    for (int b = ch*32; b < ch*32+32; ++b) sx += px[b*32 + c];
    lx[t] = sx;
  }
  {  // e: counter c = t&7, chunk = t>>3 (32 chunks x 32 blocks = NBE)
    int c = t & 7, ch = t >> 3;
    float se = 0.f;
    for (int b = ch*32; b < ch*32+32; ++b) se += pe[b*8 + c];
    le[t] = se;
  }
  __syncthreads();
  if (t < 16){
    float sum = 0.f, sq = 0.f;
    #pragma unroll
    for (int ch=0; ch<8; ++ch){ sum += lx[ch*32 + t]; sq += lx[ch*32 + 16 + t]; }
    float mean = sum / (float)n;
    float var  = sq / (float)n - mean*mean;
    float sc = g_n[t] * rsqrtf(var + 1e-5f);
    st[40+t] = sc; st[56+t] = b_n[t] - mean*sc;
  } else if (t < 20){
    int f = t-16;
    float sum = 0.f, sq = 0.f;
    #pragma unroll
    for (int ch=0; ch<32; ++ch){ sum += le[ch*8 + f]; sq += le[ch*8 + 4 + f]; }
    float mean = sum / (float)e;
    float var  = sq / (float)e - mean*mean;
    float sc = g_e[f] * rsqrtf(var + 1e-5f);
    st[72+f] = sc; st[76+f] = b_e[f] - mean*sc;
  }
}

// rp[i] = prefix(cnt)[i] + i  -> each node's segment has deg+1 slots (self loop last)
__global__ __launch_bounds__(TPB) void k_scan_a(const int* __restrict__ cnt, int* __restrict__ rp,
                                                int* __restrict__ part, int n){
  __shared__ int lds[TPB];
  int t = threadIdx.x;
  int base = blockIdx.x*2048 + t*8;
  int v[8]; int run = 0;
  #pragma unroll
  for (int j=0;j<8;++j){
    int idx = base + j;
    v[j] = run;
    run += (idx < n) ? cnt[idx] : 0;
  }
  lds[t] = run;
  __syncthreads();
  for (int off=1; off<TPB; off<<=1){
    int add = (t >= off) ? lds[t-off] : 0;
    __syncthreads();
    lds[t] += add;
    __syncthreads();
  }
  int excl = lds[t] - run;
  if (t == TPB-1) part[blockIdx.x] = lds[t];
  #pragma unroll
  for (int j=0;j<8;++j){
    int idx = base + j;
    if (idx < n) rp[idx] = v[j] + excl + idx;   // +idx: self-loop slots
  }
}

// finalize rp: each thread sums its chunk's part-prefix from the (L1-hot) part
// array — replaces the serial 1-thread scan_b kernel + a launch.
__global__ __launch_bounds__(TPB) void k_scan_c(int* __restrict__ rp, const int* __restrict__ part, int n, int nb){
  int idx = blockIdx.x*blockDim.x + threadIdx.x;
  if (idx < n){
    int chunk = idx >> 11;
    int add = 0;
    for (int b = 0; b < chunk; ++b) add += part[b];
    rp[idx] += add;
  } else if (idx == n){
    int tot = 0;
    for (int b = 0; b < nb; ++b) tot += part[b];
    rp[n] = tot + n;
  }
}

// atomic-free scatter: pos = rp[dst] + rank (rank recorded during k_edge0).
// Plain store: csr_se is read right after by k_post — keep it L2-resident.
__global__ __launch_bounds__(TPB) void k_scatter(const int* __restrict__ ei, const int* __restrict__ rank,
                        const int* __restrict__ rp, int2* __restrict__ csr_se, int E){
  for (int e = blockIdx.x*blockDim.x + threadIdx.x; e < E; e += gridDim.x*blockDim.x){
    int srcv = ei[e];
    int d    = ei[E + e];
    int pos = rp[d] + rank[e];
    csr_se[pos] = make_int2(srcv, e);
  }
}

// per-node expansion: 16 lanes per node (deg~10). csr_se -> csr_src + normalized
// csr_ea, plus self-loop entry {src=node, ea=mean of incoming} at segment end.
__global__ __launch_bounds__(TPB) void k_post(const int2* __restrict__ csr_se, const float4* __restrict__ ea,
                        const float* __restrict__ st, const int* __restrict__ rp,
                        int* __restrict__ csr_src, float4* __restrict__ csr_ea, int n){
  int lane = threadIdx.x & 63;
  int l16 = lane & 15;
  int node = (blockIdx.x*4 + (threadIdx.x >> 6))*4 + (lane >> 4);
  if (node >= n) return;
  float s0=st[72], s1=st[73], s2=st[74], s3=st[75];
  float h0=st[76], h1=st[77], h2=st[78], h3=st[79];
  int ib = rp[node], ie1 = rp[node+1] - 1;   // real edges [ib, ie1), self slot at ie1
  float4 sum = make_float4(0.f,0.f,0.f,0.f);
  for (int i = ib + l16; i < ie1; i += 16){
    int2 se = csr_se[i];
    float4 v = ea[se.y];
    float4 nv = make_float4(fmaf(v.x,s0,h0), fmaf(v.y,s1,h1), fmaf(v.z,s2,h2), fmaf(v.w,s3,h3));
    csr_src[i] = se.x;
    csr_ea[i] = nv;
    sum.x += nv.x; sum.y += nv.y; sum.z += nv.z; sum.w += nv.w;
  }
  #pragma unroll
  for (int m=1;m<16;m<<=1){
    sum.x += __shfl_xor(sum.x, m);
    sum.y += __shfl_xor(sum.y, m);
    sum.z += __shfl_xor(sum.z, m);
    sum.w += __shfl_xor(sum.w, m);
  }
  if (l16 == 0){
    int deg = ie1 - ib;
    float ic = 1.f / fmaxf((float)deg, 1.f);
    csr_src[ie1] = node;
    csr_ea[ie1] = make_float4(sum.x*ic, sum.y*ic, sum.z*ic, sum.w*ic);
  }
}

// ---------------- dual GEMM: xl(bf16) = X@Wl+bl, xr(f32) = X@Wr+br -------------
// float4 X-loads into NAMED variables (no arrays/pointer-selects — R8 lesson).
// xl written as packed bf16 rows (128B/row) to halve the conv gather bytes.
#define FMA16(i, xv) {                          \
    acc[i][0]  = fmaf(xv, wa.x, acc[i][0]);     \
    acc[i][1]  = fmaf(xv, wa.y, acc[i][1]);     \
    acc[i][2]  = fmaf(xv, wa.z, acc[i][2]);     \
    acc[i][3]  = fmaf(xv, wa.w, acc[i][3]);     \
    acc[i][4]  = fmaf(xv, wb.x, acc[i][4]);     \
    acc[i][5]  = fmaf(xv, wb.y, acc[i][5]);     \
    acc[i][6]  = fmaf(xv, wb.z, acc[i][6]);     \
    acc[i][7]  = fmaf(xv, wb.w, acc[i][7]);     \
    acc[i][8]  = fmaf(xv, wc.x, acc[i][8]);     \
    acc[i][9]  = fmaf(xv, wc.y, acc[i][9]);     \
    acc[i][10] = fmaf(xv, wc.z, acc[i][10]);    \
    acc[i][11] = fmaf(xv, wc.w, acc[i][11]);    \
    acc[i][12] = fmaf(xv, wd.x, acc[i][12]);    \
    acc[i][13] = fmaf(xv, wd.y, acc[i][13]);    \
    acc[i][14] = fmaf(xv, wd.z, acc[i][14]);    \
    acc[i][15] = fmaf(xv, wd.w, acc[i][15]); }
#define KSTEP(kk, c0_, c1_, c2_, c3_) {                                        \
    const float4* w4 = (const float4*)&Wlds[(k4*4+kk)*128 + c16];              \
    float4 wa = w4[0], wb = w4[1], wc = w4[2], wd = w4[3];                     \
    FMA16(0, c0_); FMA16(1, c1_); FMA16(2, c2_); FMA16(3, c3_); }

template<int K, bool BN>
__global__ __launch_bounds__(TPB) void k_gemm(const float* __restrict__ X,
    const float* __restrict__ Wl, const float* __restrict__ bl,
    const float* __restrict__ Wr, const float* __restrict__ br,
    const float* __restrict__ st,
    u16* __restrict__ xl, float* __restrict__ xr, int nrows){
  __shared__ __align__(16) float Wlds[K*128];
  __shared__ float blds[128];
  __shared__ float bns[16], bnb[16];
  int t = threadIdx.x;
  for (int idx = t; idx < K*128; idx += TPB){
    int k = idx >> 7, j = idx & 127;
    Wlds[idx] = (j < 64) ? Wl[k*64 + j] : Wr[k*64 + (j - 64)];
  }
  if (t < 64) blds[t] = bl[t];
  else if (t < 128) blds[t] = br[t - 64];
  if (BN){ if (t >= 128 && t < 144){ bns[t-128] = st[40 + (t-128)]; bnb[t-128] = st[56 + (t-128)]; } }
  __syncthreads();
  int rg = t & 31, c = t >> 5;
  int c16 = c*16;
  int r0 = blockIdx.x*128 + rg*4;
  int r[4];
  #pragma unroll
  for (int i=0;i<4;++i){ int ri = r0 + i; r[i] = (ri < nrows) ? ri : (nrows-1); }
  float acc[4][16];
  #pragma unroll
  for (int i=0;i<4;++i){
    #pragma unroll
    for (int j=0;j<16;++j) acc[i][j]=0.f;
  }
  #pragma unroll 2
  for (int k4=0; k4<K/4; ++k4){
    float4 xa = *(const float4*)&X[(size_t)r[0]*K + k4*4];
    float4 xb = *(const float4*)&X[(size_t)r[1]*K + k4*4];
    float4 xc = *(const float4*)&X[(size_t)r[2]*K + k4*4];
    float4 xd = *(const float4*)&X[(size_t)r[3]*K + k4*4];
    if (BN){
      float s0=bns[k4*4+0], b0=bnb[k4*4+0];
      float s1=bns[k4*4+1], b1=bnb[k4*4+1];
      float s2=bns[k4*4+2], b2=bnb[k4*4+2];
      float s3=bns[k4*4+3], b3=bnb[k4*4+3];
      xa.x=fmaf(xa.x,s0,b0); xa.y=fmaf(xa.y,s1,b1); xa.z=fmaf(xa.z,s2,b2); xa.w=fmaf(xa.w,s3,b3);
      xb.x=fmaf(xb.x,s0,b0); xb.y=fmaf(xb.y,s1,b1); xb.z=fmaf(xb.z,s2,b2); xb.w=fmaf(xb.w,s3,b3);
      xc.x=fmaf(xc.x,s0,b0); xc.y=fmaf(xc.y,s1,b1); xc.z=fmaf(xc.z,s2,b2); xc.w=fmaf(xc.w,s3,b3);
      xd.x=fmaf(xd.x,s0,b0); xd.y=fmaf(xd.y,s1,b1); xd.z=fmaf(xd.z,s2,b2); xd.w=fmaf(xd.w,s3,b3);
    }
    KSTEP(0, xa.x, xb.x, xc.x, xd.x);
    KSTEP(1, xa.y, xb.y, xc.y, xd.y);
    KSTEP(2, xa.z, xb.z, xc.z, xd.z);
    KSTEP(3, xa.w, xb.w, xc.w, xd.w);
  }
  if (c16 < 64){
    // xl: pack 16 biased outputs to bf16, two uint4 stores per row
    #pragma unroll
    for (int i=0;i<4;++i){
      if (r0 + i < nrows){
        u16* qb = &xl[(size_t)(r0+i)*64 + c16];
        uint4 p0, p1;
        p0.x = pack_bf16(acc[i][0] +blds[c16+0],  acc[i][1] +blds[c16+1]);
        p0.y = pack_bf16(acc[i][2] +blds[c16+2],  acc[i][3] +blds[c16+3]);
        p0.z = pack_bf16(acc[i][4] +blds[c16+4],  acc[i][5] +blds[c16+5]);
        p0.w = pack_bf16(acc[i][6] +blds[c16+6],  acc[i][7] +blds[c16+7]);
        p1.x = pack_bf16(acc[i][8] +blds[c16+8],  acc[i][9] +blds[c16+9]);
        p1.y = pack_bf16(acc[i][10]+blds[c16+10], acc[i][11]+blds[c16+11]);
        p1.z = pack_bf16(acc[i][12]+blds[c16+12], acc[i][13]+blds[c16+13]);
        p1.w = pack_bf16(acc[i][14]+blds[c16+14], acc[i][15]+blds[c16+15]);
        ((uint4*)qb)[0] = p0;
        ((uint4*)qb)[1] = p1;
      }
    }
  } else {
    int cb = c16 - 64;
    #pragma unroll
    for (int i=0;i<4;++i){
      if (r0 + i < nrows){
        float* q = &xr[(size_t)(r0+i)*64 + cb];
        ((float4*)q)[0] = make_float4(acc[i][0]+blds[c16+0],  acc[i][1]+blds[c16+1],
                                      acc[i][2]+blds[c16+2],  acc[i][3]+blds[c16+3]);
        ((float4*)q)[1] = make_float4(acc[i][4]+blds[c16+4],  acc[i][5]+blds[c16+5],
                                      acc[i][6]+blds[c16+6],  acc[i][7]+blds[c16+7]);
        ((float4*)q)[2] = make_float4(acc[i][8]+blds[c16+8],  acc[i][9]+blds[c16+9],
                                      acc[i][10]+blds[c16+10],acc[i][11]+blds[c16+11]);
        ((float4*)q)[3] = make_float4(acc[i][12]+blds[c16+12],acc[i][13]+blds[c16+13],
                                      acc[i][14]+blds[c16+14],acc[i][15]+blds[c16+15]);
      }
    }
  }
}

// ---------------- GATv2 conv: 2 channels/lane, 2 edges/wave (R12 best) --------
// Lanes 0-31 = edge A, lanes 32-63 = edge B of the SAME node; each lane holds
// channels (2*l32, 2*l32+1) as one bf16x2 dword — gather is dword-class
// (R11 lesson: sub-dword ushort gathers are a TA slow path; R13 lesson:
// 4-edge quads lose to per-node epilogue cost + occupancy drop). Per edge-pair:
// 1 gather instr, 2 shuffles (head reduce over 4 lanes), 1 exp/lane. Halves
// combined once per node via shfl_xor 32. Odd tail: clamped idx + masked w.
#define LOADP(e_, u_, i_) { int idx_ = (i_) + half; int s_ = csr_src[idx_];     \
    e_ = csr_ea[idx_];                                                          \
    u_ = *(const unsigned*)&xl[(size_t)s_*64 + (l32<<1)]; }
#define PROCP(e_, u_) {                                                         \
    float ax_ = __uint_as_float((u_) << 16);                                    \
    float ay_ = __uint_as_float((u_) & 0xffff0000u);                            \
    float v0_ = ax_ + xrx, v1_ = ay_ + xry;                                     \
    v0_ = fmaf(e_.x,we0x, fmaf(e_.y,we1x, fmaf(e_.z,we2x, fmaf(e_.w,we3x, v0_))));\
    v1_ = fmaf(e_.x,we0y, fmaf(e_.y,we1y, fmaf(e_.z,we2y, fmaf(e_.w,we3y, v1_))));\
    v0_ = lrelu(v0_); v1_ = lrelu(v1_);                                         \
    float p_ = fmaf(v0_, attx, v1_*atty);                                       \
    p_ += __shfl_xor(p_,1); p_ += __shfl_xor(p_,2);                             \
    float w_ = __expf(p_);                                                      \
    S += w_; Ox = fmaf(w_,ax_,Ox); Oy = fmaf(w_,ay_,Oy); }

__global__ __launch_bounds__(TPB) void k_conv(
    const u16* __restrict__ xl, const float* __restrict__ xr,
    const int* __restrict__ rp, const int* __restrict__ csr_src, const float4* __restrict__ csr_ea,
    const float* __restrict__ We, const float* __restrict__ att, const float* __restrict__ bc,
    float* __restrict__ xout, int n){
  int lane = threadIdx.x & 63;
  int half = lane >> 5;
  int l32  = lane & 31;
  int c0 = l32*2, c1 = c0+1;
  int gw = blockIdx.x*4 + (threadIdx.x >> 6);
  int nw = gridDim.x*4;
  float we0x = We[c0],      we0y = We[c1];
  float we1x = We[64+c0],   we1y = We[64+c1];
  float we2x = We[128+c0],  we2y = We[128+c1];
  float we3x = We[192+c0],  we3y = We[192+c1];
  float attx = att[c0], atty = att[c1];
  float bcx  = bc[c0],  bcy  = bc[c1];

  for (int node = gw; node < n; node += nw){
    int ib = RF(rp[node]);
    int ie = RF(rp[node+1]);
    int cnt = ie - ib;
    float2 xrv = *(const float2*)&xr[(size_t)node*64 + c0];
    float xrx = xrv.x, xry = xrv.y;
    float S = 0.f, Ox = 0.f, Oy = 0.f;
    float4 e0, e1, e2; unsigned u0=0, u1=0, u2=0;
    int npf = cnt >> 1;               // full pairs
    int iendf = ib + npf*2;
    if (npf > 0) LOADP(e0,u0, ib);
    if (npf > 1) LOADP(e1,u1, ib+2);
    if (npf > 2) LOADP(e2,u2, ib+4);
    int i = ib;
    for (; i+6 <= iendf; i += 6){
      PROCP(e0,u0); if (i+6  < iendf) LOADP(e0,u0, i+6);
      PROCP(e1,u1); if (i+8  < iendf) LOADP(e1,u1, i+8);
      PROCP(e2,u2); if (i+10 < iendf) LOADP(e2,u2, i+10);
    }
    int rem = (iendf - i) >> 1;       // 0..2 remaining full pairs
    if (rem > 0) PROCP(e0,u0);
    if (rem > 1) PROCP(e1,u1);
    if (cnt & 1){
      // odd tail: half B reads a clamped duplicate and its w is masked to 0
      int idx_ = min(iendf + half, ie - 1);
      int s_ = csr_src[idx_];
      float4 et = csr_ea[idx_];
      unsigned ut = *(const unsigned*)&xl[(size_t)s_*64 + (l32<<1)];
      float ax_ = __uint_as_float(ut << 16);
      float ay_ = __uint_as_float(ut & 0xffff0000u);
      float v0_ = ax_ + xrx, v1_ = ay_ + xry;
      v0_ = fmaf(et.x,we0x, fmaf(et.y,we1x, fmaf(et.z,we2x, fmaf(et.w,we3x, v0_))));
      v1_ = fmaf(et.x,we0y, fmaf(et.y,we1y, fmaf(et.z,we2y, fmaf(et.w,we3y, v1_))));
      v0_ = lrelu(v0_); v1_ = lrelu(v1_);
      float p_ = fmaf(v0_, attx, v1_*atty);
      p_ += __shfl_xor(p_,1); p_ += __shfl_xor(p_,2);
      float w_ = (half == 0) ? __expf(p_) : 0.f;
      S += w_; Ox = fmaf(w_,ax_,Ox); Oy = fmaf(w_,ay_,Oy);
    }
    // combine the two edge-halves
    S  += __shfl_xor(S, 32);
    Ox += __shfl_xor(Ox, 32);
    Oy += __shfl_xor(Oy, 32);
    if (half == 0){
      float2 o;
      o.x = lrelu(Ox / S + bcx);
      o.y = lrelu(Oy / S + bcy);
      *(float2*)&xout[(size_t)node*64 + c0] = o;
    }
  }
}

// ---------------- fused readout: one block per graph ----------------
// batch is sorted -> group g occupies a contiguous range found by binary search.
__global__ __launch_bounds__(1024) void k_readout(const float* __restrict__ x,
    const int* __restrict__ batch, const float* __restrict__ tin,
    const float* __restrict__ Wout, const float* __restrict__ bout,
    float* __restrict__ out, int n){
  int g = blockIdx.x;
  int lane = threadIdx.x & 63, wid = threadIdx.x >> 6;   // 16 waves
  int lo, hi;
  { int a=0, b=n; while (a<b){ int m=(a+b)>>1; if (batch[m] <  g) a=m+1; else b=m; } lo=a; }
  { int a=lo, b=n; while (a<b){ int m=(a+b)>>1; if (batch[m] <= g) a=m+1; else b=m; } hi=a; }
  float t = tin[0];
  __shared__ float red[16][64];
  float mx = -INFINITY;
  for (int nd = lo + wid; nd < hi; nd += 16)
    mx = fmaxf(mx, x[(size_t)nd*64 + lane]*t);
  red[wid][lane] = mx;
  __syncthreads();
  mx = -INFINITY;
  #pragma unroll
  for (int wv=0; wv<16; ++wv) mx = fmaxf(mx, red[wv][lane]);
  __syncthreads();
  float ld = 0.f, ln = 0.f;
  for (int nd = lo + wid; nd < hi; nd += 16){
    float xv = x[(size_t)nd*64 + lane];
    float w = __expf(xv*t - mx);
    ld += w; ln = fmaf(w, xv, ln);
  }
  red[wid][lane] = ld;
  __syncthreads();
  float den = 0.f;
  #pragma unroll
  for (int wv=0; wv<16; ++wv) den += red[wv][lane];
  __syncthreads();
  red[wid][lane] = ln;
  __syncthreads();
  if (wid == 0){
    float num = 0.f;
    #pragma unroll
    for (int wv=0; wv<16; ++wv) num += red[wv][lane];
    float agg = (hi > lo) ? num/den : 0.f;
    #pragma unroll
    for (int c=0;c<4;++c){
      float p = agg * Wout[lane*4 + c];
      #pragma unroll
      for (int m=1;m<64;m<<=1) p += __shfl_xor(p, m);
      if (lane == 0) out[g*4 + c] = p + bout[c];
    }
  }
}

// ---------------- launch ----------------
extern "C" void kernel_launch(void* const* d_in, const int* in_sizes, int n_in,
                              void* d_out, int out_size, void* d_ws, size_t ws_size,
                              hipStream_t stream){
  const float* x     = (const float*)d_in[0];
  const int*   ei    = (const int*)d_in[1];
  const float* ea    = (const float*)d_in[2];
  const int*   batch = (const int*)d_in[3];
  const float* g_n = (const float*)d_in[4];
  const float* b_n = (const float*)d_in[5];
  const float* g_e = (const float*)d_in[6];
  const float* b_e = (const float*)d_in[7];
  const float* Wl[3]  = {(const float*)d_in[8],  (const float*)d_in[15], (const float*)d_in[22]};
  const float* bl[3]  = {(const float*)d_in[9],  (const float*)d_in[16], (const float*)d_in[23]};
  const float* Wr[3]  = {(const float*)d_in[10], (const float*)d_in[17], (const float*)d_in[24]};
  const float* br[3]  = {(const float*)d_in[11], (const float*)d_in[18], (const float*)d_in[25]};
  const float* We[3]  = {(const float*)d_in[12], (const float*)d_in[19], (const float*)d_in[26]};
  const float* att[3] = {(const float*)d_in[13], (const float*)d_in[20], (const float*)d_in[27]};
  const float* bc[3]  = {(const float*)d_in[14], (const float*)d_in[21], (const float*)d_in[28]};
  const float* tin  = (const float*)d_in[29];
  const float* Wout = (const float*)d_in[30];
  const float* bout = (const float*)d_in[31];
  float* out = (float*)d_out;

  const int n = in_sizes[0] / 16;   // nodes
  const int E = in_sizes[1] / 2;    // edges

  char* w = (char*)d_ws;
  size_t off = 0;
  auto alloc = [&](size_t bytes)->char*{
    char* p = w + off;
    off = (off + bytes + 255) & ~(size_t)255;
    return p;
  };
  int*      cnt      = (int*)alloc((size_t)n*4);       // must be zeroed
  size_t zero_end = off;
  float*    st       = (float*)alloc(128*4);
  int*      rank     = (int*)alloc((size_t)E*4);
  float*    px       = (float*)alloc((size_t)NBX*32*4);
  float*    pe       = (float*)alloc((size_t)NBE*8*4);
  int*      rp       = (int*)alloc(((size_t)n+1)*4);
  int*      part     = (int*)alloc(64*4);
  int2*     csr_se   = (int2*)alloc((size_t)(E+n)*8);
  int*      csr_src  = (int*)alloc((size_t)(E+n)*4);
  float4*   csr_ea   = (float4*)alloc((size_t)(E+n)*16);
  u16*      xlb      = (u16*)alloc((size_t)n*64*2);
  float*    xrb      = (float*)alloc((size_t)n*64*4);
  float*    xbuf     = (float*)alloc((size_t)n*64*4);
  if (off > ws_size) return;  // insufficient workspace -> clean (visible) failure

  hipMemsetAsync(d_ws, 0, zero_end, stream);

  k_stats_x<<<NBX, TPB, 0, stream>>>(x, px, n);
  k_edge0<<<NBE, TPB, 0, stream>>>(ea, ei, pe, cnt, rank, E);
  k_finalize<<<1, TPB, 0, stream>>>(g_n, b_n, g_e, b_e, px, pe, st, n, E);
  int nb = (n + 2047) / 2048;
  k_scan_a<<<nb, TPB, 0, stream>>>(cnt, rp, part, n);
  k_scan_c<<<(n + 1 + TPB - 1)/TPB, TPB, 0, stream>>>(rp, part, n, nb);
  k_scatter<<<2048, TPB, 0, stream>>>(ei, rank, rp, csr_se, E);
  k_post<<<(n + 15)/16, TPB, 0, stream>>>(csr_se, (const float4*)ea, st, rp, csr_src, (float4*)csr_ea, n);

  int gb = (n + 127)/128;
  for (int l=0; l<3; ++l){
    if (l == 0)
      k_gemm<16,true><<<gb, TPB, 0, stream>>>(x, Wl[0], bl[0], Wr[0], br[0], st, xlb, xrb, n);
    else
      k_gemm<64,false><<<gb, TPB, 0, stream>>>(xbuf, Wl[l], bl[l], Wr[l], br[l], st, xlb, xrb, n);
    k_conv<<<CONVB, TPB, 0, stream>>>(xlb, xrb, rp, csr_src, csr_ea,
                                      We[l], att[l], bc[l], xbuf, n);
  }

  k_readout<<<64, 1024, 0, stream>>>(xbuf, batch, tin, Wout, bout, out, n);
}